// Round 1
// baseline (1807.784 us; speedup 1.0000x reference)
//
#include <hip/hip_runtime.h>
#include <math.h>

#define EPS_BN   1e-5f
#define EPS_NORM 1e-12f

constexpr int B_ = 8192, D_ = 2048, H_ = 2048, Z_ = 256, E_ = 5, C_ = 100;

// ---------------------------------------------------------------------------
// K0: zero the routing counters (ws is re-poisoned to 0xAA before every call)
__global__ void zero_counts(int* counts) {
    if (threadIdx.x < 8) counts[threadIdx.x] = 0;
}

// ---------------------------------------------------------------------------
// Generic fp32 tiled GEMM: C = [optional BN+ReLU](A[M,K] @ W[K,N] + bias)
// BM=BN=64, BK=16, 256 threads (16x16), 4x4 micro-tile per thread.
template<bool BN_RELU>
__global__ __launch_bounds__(256)
void gemm_kernel(const float* __restrict__ A, const float* __restrict__ W,
                 const float* __restrict__ bias,
                 const float* __restrict__ g, const float* __restrict__ bt,
                 const float* __restrict__ mean, const float* __restrict__ var,
                 float* __restrict__ Cout, int M, int N, int K)
{
    constexpr int BM = 64, BN = 64, BK = 16, TM = 4, TN = 4;
    __shared__ float As[BK][BM + 4];
    __shared__ float Ws[BK][BN + 4];
    const int tid = threadIdx.y * 16 + threadIdx.x;
    const int rowBase = blockIdx.y * BM;
    const int colBase = blockIdx.x * BN;
    const int aRow = tid >> 2, aCol = (tid & 3) * 4;     // 64 rows x 16 cols, float4
    const int wRow = tid >> 4, wCol = (tid & 15) * 4;    // 16 rows x 64 cols, float4
    float acc[TM][TN] = {};

    for (int k0 = 0; k0 < K; k0 += BK) {
        const float4 av = *reinterpret_cast<const float4*>(
            &A[(size_t)(rowBase + aRow) * K + k0 + aCol]);
        As[aCol + 0][aRow] = av.x; As[aCol + 1][aRow] = av.y;
        As[aCol + 2][aRow] = av.z; As[aCol + 3][aRow] = av.w;
        const float4 wv = *reinterpret_cast<const float4*>(
            &W[(size_t)(k0 + wRow) * N + colBase + wCol]);
        *reinterpret_cast<float4*>(&Ws[wRow][wCol]) = wv;
        __syncthreads();
#pragma unroll
        for (int kk = 0; kk < BK; ++kk) {
            float a[TM], w[TN];
#pragma unroll
            for (int i = 0; i < TM; ++i) a[i] = As[kk][threadIdx.y * TM + i];
#pragma unroll
            for (int j = 0; j < TN; ++j) w[j] = Ws[kk][threadIdx.x * TN + j];
#pragma unroll
            for (int i = 0; i < TM; ++i)
#pragma unroll
                for (int j = 0; j < TN; ++j)
                    acc[i][j] = fmaf(a[i], w[j], acc[i][j]);
        }
        __syncthreads();
    }
#pragma unroll
    for (int i = 0; i < TM; ++i) {
        const int row = rowBase + threadIdx.y * TM + i;
#pragma unroll
        for (int j = 0; j < TN; ++j) {
            const int col = colBase + threadIdx.x * TN + j;
            float v = acc[i][j] + bias[col];
            if constexpr (BN_RELU) {
                v = (v - mean[col]) * rsqrtf(var[col] + EPS_BN) * g[col] + bt[col];
                v = fmaxf(v, 0.f);
            }
            Cout[(size_t)row * N + col] = v;
        }
    }
}

// ---------------------------------------------------------------------------
// K2b: row-wise L2 normalize [B,256]; write to ws copy and to output slice.
__global__ __launch_bounds__(256)
void norm_rows(const float* __restrict__ in, float* __restrict__ ws_zp,
               float* __restrict__ out_zp)
{
    const int row = blockIdx.x, t = threadIdx.x;
    const float v = in[(size_t)row * Z_ + t];
    float s = v * v;
    for (int off = 32; off; off >>= 1) s += __shfl_down(s, off);
    __shared__ float wsum[4];
    if ((t & 63) == 0) wsum[t >> 6] = s;
    __syncthreads();
    const float tot = wsum[0] + wsum[1] + wsum[2] + wsum[3];
    const float scale = 1.f / fmaxf(sqrtf(tot), EPS_NORM);
    const float z = v * scale;
    ws_zp[(size_t)row * Z_ + t] = z;
    out_zp[(size_t)row * Z_ + t] = z;
}

// ---------------------------------------------------------------------------
// K3: pattern logits (vs 5 unit prototypes), argmax route, compaction lists.
// One wave (64 lanes) per row; 4 rows per 256-thread block.
__global__ __launch_bounds__(256)
void logits_route(const float* __restrict__ zp, const float* __restrict__ pProto,
                  float* __restrict__ out_lp, int* __restrict__ counts,
                  int* __restrict__ lists)
{
    const int wave = threadIdx.x >> 6, lane = threadIdx.x & 63;
    const int b = blockIdx.x * 4 + wave;
    const float4 z = *reinterpret_cast<const float4*>(&zp[(size_t)b * Z_ + lane * 4]);
    float p[E_];
#pragma unroll
    for (int e = 0; e < E_; ++e) {
        const float4 pr = *reinterpret_cast<const float4*>(&pProto[(size_t)e * Z_ + lane * 4]);
        float s = z.x * pr.x + z.y * pr.y + z.z * pr.z + z.w * pr.w;
        for (int off = 32; off; off >>= 1) s += __shfl_down(s, off);
        p[e] = s;
    }
    if (lane == 0) {
        int best = 0; float bv = p[0];
#pragma unroll
        for (int e = 1; e < E_; ++e) if (p[e] > bv) { bv = p[e]; best = e; }
#pragma unroll
        for (int e = 0; e < E_; ++e) out_lp[(size_t)b * E_ + e] = p[e];
        const int idx = atomicAdd(&counts[best], 1);
        lists[best * B_ + idx] = b;
    }
}

// K3b: exclusive prefix over 5 counts.
__global__ void calc_offsets(const int* __restrict__ counts, int* __restrict__ offsets) {
    if (threadIdx.x == 0) {
        int acc = 0;
        for (int e = 0; e < E_; ++e) { offsets[e] = acc; acc += counts[e]; }
        offsets[E_] = acc;
    }
}

// ---------------------------------------------------------------------------
// K4: per-expert gathered GEMM-A: h2c = relu(BN(zp[rows] @ cW1[e] + cb1[e]))
// K = Z_(256), N = H_(2048). Rows gathered via lists[e].
__global__ __launch_bounds__(256)
void expert_gemmA(const float* __restrict__ zp, const float* __restrict__ cW1,
                  const float* __restrict__ cb1, const float* __restrict__ cg,
                  const float* __restrict__ cbt, const float* __restrict__ cm,
                  const float* __restrict__ cv,
                  const int* __restrict__ lists, const int* __restrict__ counts,
                  const int* __restrict__ offsets, float* __restrict__ h2c)
{
    constexpr int BM = 64, BN = 64, BK = 16, TM = 4, TN = 4;
    const int e = blockIdx.z;
    const int cnt = counts[e];
    const int rowTile = blockIdx.y * BM;
    if (rowTile >= cnt) return;
    __shared__ float As[BK][BM + 4];
    __shared__ float Ws[BK][BN + 4];
    const int tid = threadIdx.y * 16 + threadIdx.x;
    const int colBase = blockIdx.x * BN;
    const int aRow = tid >> 2, aCol = (tid & 3) * 4;
    const int wRow = tid >> 4, wCol = (tid & 15) * 4;
    const int gi = rowTile + aRow;
    const int srcRow = (gi < cnt) ? lists[e * B_ + gi] : -1;
    const float* W = cW1 + (size_t)e * Z_ * H_;
    float acc[TM][TN] = {};

    for (int k0 = 0; k0 < Z_; k0 += BK) {
        float4 av = make_float4(0.f, 0.f, 0.f, 0.f);
        if (srcRow >= 0)
            av = *reinterpret_cast<const float4*>(&zp[(size_t)srcRow * Z_ + k0 + aCol]);
        As[aCol + 0][aRow] = av.x; As[aCol + 1][aRow] = av.y;
        As[aCol + 2][aRow] = av.z; As[aCol + 3][aRow] = av.w;
        const float4 wv = *reinterpret_cast<const float4*>(
            &W[(size_t)(k0 + wRow) * H_ + colBase + wCol]);
        *reinterpret_cast<float4*>(&Ws[wRow][wCol]) = wv;
        __syncthreads();
#pragma unroll
        for (int kk = 0; kk < BK; ++kk) {
            float a[TM], w[TN];
#pragma unroll
            for (int i = 0; i < TM; ++i) a[i] = As[kk][threadIdx.y * TM + i];
#pragma unroll
            for (int j = 0; j < TN; ++j) w[j] = Ws[kk][threadIdx.x * TN + j];
#pragma unroll
            for (int i = 0; i < TM; ++i)
#pragma unroll
                for (int j = 0; j < TN; ++j)
                    acc[i][j] = fmaf(a[i], w[j], acc[i][j]);
        }
        __syncthreads();
    }
    const int base = offsets[e];
#pragma unroll
    for (int i = 0; i < TM; ++i) {
        const int gr = rowTile + threadIdx.y * TM + i;
        if (gr >= cnt) continue;
#pragma unroll
        for (int j = 0; j < TN; ++j) {
            const int col = colBase + threadIdx.x * TN + j;
            float v = acc[i][j] + cb1[e * H_ + col];
            v = (v - cm[e * H_ + col]) * rsqrtf(cv[e * H_ + col] + EPS_BN)
                * cg[e * H_ + col] + cbt[e * H_ + col];
            v = fmaxf(v, 0.f);
            h2c[(size_t)(base + gr) * H_ + col] = v;
        }
    }
}

// ---------------------------------------------------------------------------
// K5: per-expert GEMM-B over compacted contiguous rows:
// z2c = h2c[rows] @ cW2[e] + cb2[e].  K = H_(2048), N = Z_(256).
__global__ __launch_bounds__(256)
void expert_gemmB(const float* __restrict__ h2c, const float* __restrict__ cW2,
                  const float* __restrict__ cb2, const int* __restrict__ counts,
                  const int* __restrict__ offsets, float* __restrict__ z2c)
{
    constexpr int BM = 64, BN = 64, BK = 16, TM = 4, TN = 4;
    const int e = blockIdx.z;
    const int cnt = counts[e];
    const int rowTile = blockIdx.y * BM;
    if (rowTile >= cnt) return;
    __shared__ float As[BK][BM + 4];
    __shared__ float Ws[BK][BN + 4];
    const int tid = threadIdx.y * 16 + threadIdx.x;
    const int colBase = blockIdx.x * BN;
    const int aRow = tid >> 2, aCol = (tid & 3) * 4;
    const int wRow = tid >> 4, wCol = (tid & 15) * 4;
    const float* A = h2c + (size_t)offsets[e] * H_;
    const float* W = cW2 + (size_t)e * H_ * Z_;
    float acc[TM][TN] = {};

    for (int k0 = 0; k0 < H_; k0 += BK) {
        float4 av = make_float4(0.f, 0.f, 0.f, 0.f);
        if (rowTile + aRow < cnt)
            av = *reinterpret_cast<const float4*>(&A[(size_t)(rowTile + aRow) * H_ + k0 + aCol]);
        As[aCol + 0][aRow] = av.x; As[aCol + 1][aRow] = av.y;
        As[aCol + 2][aRow] = av.z; As[aCol + 3][aRow] = av.w;
        const float4 wv = *reinterpret_cast<const float4*>(
            &W[(size_t)(k0 + wRow) * Z_ + colBase + wCol]);
        *reinterpret_cast<float4*>(&Ws[wRow][wCol]) = wv;
        __syncthreads();
#pragma unroll
        for (int kk = 0; kk < BK; ++kk) {
            float a[TM], w[TN];
#pragma unroll
            for (int i = 0; i < TM; ++i) a[i] = As[kk][threadIdx.y * TM + i];
#pragma unroll
            for (int j = 0; j < TN; ++j) w[j] = Ws[kk][threadIdx.x * TN + j];
#pragma unroll
            for (int i = 0; i < TM; ++i)
#pragma unroll
                for (int j = 0; j < TN; ++j)
                    acc[i][j] = fmaf(a[i], w[j], acc[i][j]);
        }
        __syncthreads();
    }
#pragma unroll
    for (int i = 0; i < TM; ++i) {
        const int gr = rowTile + threadIdx.y * TM + i;
        if (gr >= cnt) continue;
#pragma unroll
        for (int j = 0; j < TN; ++j) {
            const int col = colBase + threadIdx.x * TN + j;
            z2c[(size_t)(offsets[e] + gr) * Z_ + col] = acc[i][j] + cb2[e * Z_ + col];
        }
    }
}

// ---------------------------------------------------------------------------
// K6: per compacted row: L2-norm z2, dot vs 100 class prototypes, scatter
// to logits_class[b] and proj_feats_class[b].
__global__ __launch_bounds__(256)
void finalize(const float* __restrict__ z2c, const float* __restrict__ cProto,
              const int* __restrict__ lists, const int* __restrict__ offsets,
              float* __restrict__ out_lc, float* __restrict__ out_pf)
{
    const int c = blockIdx.x;   // compacted row index, 0..B-1 (counts sum to B)
    const int t = threadIdx.x;
    int e = 0;
#pragma unroll
    for (int k = 1; k < E_; ++k) if (c >= offsets[k]) e = k;
    const int b = lists[e * B_ + (c - offsets[e])];

    const float v = z2c[(size_t)c * Z_ + t];
    float s = v * v;
    for (int off = 32; off; off >>= 1) s += __shfl_down(s, off);
    __shared__ float wsum[4];
    if ((t & 63) == 0) wsum[t >> 6] = s;
    __syncthreads();
    const float tot = wsum[0] + wsum[1] + wsum[2] + wsum[3];
    const float scale = 1.f / fmaxf(sqrtf(tot), EPS_NORM);
    const float z = v * scale;
    out_pf[(size_t)b * Z_ + t] = z;

    __shared__ float zn[Z_];
    zn[t] = z;
    __syncthreads();
    if (t < C_) {
        const float* pr = &cProto[((size_t)e * C_ + t) * Z_];
        float acc = 0.f;
        for (int zi = 0; zi < Z_; ++zi) acc = fmaf(zn[zi], pr[zi], acc);
        out_lc[(size_t)b * C_ + t] = acc;
    }
}

// ---------------------------------------------------------------------------
extern "C" void kernel_launch(void* const* d_in, const int* in_sizes, int n_in,
                              void* d_out, int out_size, void* d_ws, size_t ws_size,
                              hipStream_t stream)
{
    const float* feats  = (const float*)d_in[0];
    const float* pW1    = (const float*)d_in[1];
    const float* pb1    = (const float*)d_in[2];
    const float* pg     = (const float*)d_in[3];
    const float* pbt    = (const float*)d_in[4];
    const float* pm     = (const float*)d_in[5];
    const float* pv     = (const float*)d_in[6];
    const float* pW2    = (const float*)d_in[7];
    const float* pb2    = (const float*)d_in[8];
    const float* pProto = (const float*)d_in[9];
    const float* cW1    = (const float*)d_in[10];
    const float* cb1    = (const float*)d_in[11];
    const float* cg     = (const float*)d_in[12];
    const float* cbt    = (const float*)d_in[13];
    const float* cm     = (const float*)d_in[14];
    const float* cv     = (const float*)d_in[15];
    const float* cW2    = (const float*)d_in[16];
    const float* cb2    = (const float*)d_in[17];
    const float* cProto = (const float*)d_in[18];

    float* ws = (float*)d_ws;
    float* h    = ws;                                   // [B,H] 16.78M f (reused as h2c)
    float* zp   = ws + (size_t)B_ * H_;                 // [B,Z] 2.10M f
    float* z2c  = zp + (size_t)B_ * Z_;                 // [B,Z] 2.10M f
    int*   counts  = (int*)(z2c + (size_t)B_ * Z_);     // 8
    int*   offsets = counts + 8;                        // 8
    int*   lists   = offsets + 8;                       // E*B = 40960

    float* out_lp = (float*)d_out;                      // [B,E]
    float* out_zp = out_lp + (size_t)B_ * E_;           // [B,Z]
    float* out_lc = out_zp + (size_t)B_ * Z_;           // [B,C]
    float* out_pf = out_lc + (size_t)B_ * C_;           // [B,Z]

    dim3 blk(16, 16);

    zero_counts<<<1, 64, 0, stream>>>(counts);
    // pattern head: h = relu(BN(feats @ pW1 + pb1))
    gemm_kernel<true><<<dim3(H_ / 64, B_ / 64), blk, 0, stream>>>(
        feats, pW1, pb1, pg, pbt, pm, pv, h, B_, H_, D_);
    // zp_unnorm = h @ pW2 + pb2   (into zp buffer, normalized in-place next)
    gemm_kernel<false><<<dim3(Z_ / 64, B_ / 64), blk, 0, stream>>>(
        h, pW2, pb2, nullptr, nullptr, nullptr, nullptr, zp, B_, Z_, H_);
    norm_rows<<<B_, 256, 0, stream>>>(zp, zp, out_zp);
    logits_route<<<B_ / 4, 256, 0, stream>>>(zp, pProto, out_lp, counts, lists);
    calc_offsets<<<1, 64, 0, stream>>>(counts, offsets);
    // routed experts (compacted): h reused as h2c
    expert_gemmA<<<dim3(H_ / 64, B_ / 64, E_), blk, 0, stream>>>(
        zp, cW1, cb1, cg, cbt, cm, cv, lists, counts, offsets, h);
    expert_gemmB<<<dim3(Z_ / 64, B_ / 64, E_), blk, 0, stream>>>(
        h, cW2, cb2, counts, offsets, z2c);
    finalize<<<B_, 256, 0, stream>>>(z2c, cProto, lists, offsets, out_lc, out_pf);
}

// Round 2
// 922.318 us; speedup vs baseline: 1.9600x; 1.9600x over previous
//
#include <hip/hip_runtime.h>
#include <math.h>

#define EPS_BN   1e-5f
#define EPS_NORM 1e-12f
#define GAP_TAU  1e-3f
#define RMAX     1024

constexpr int B_ = 8192, D_ = 2048, H_ = 2048, Z_ = 256, E_ = 5, C_ = 100;

typedef __attribute__((ext_vector_type(8))) short short8v;
typedef __attribute__((ext_vector_type(4))) float f32x4;
typedef __attribute__((ext_vector_type(8))) unsigned short ush8;
typedef __attribute__((ext_vector_type(4))) unsigned short ush4;

#define MFMA16(a,b,c) __builtin_amdgcn_mfma_f32_16x16x32_bf16(a,b,c,0,0,0)

#define GLD_LDS16(SRC, DST) \
  __builtin_amdgcn_global_load_lds((const __attribute__((address_space(1))) void*)(SRC), \
                                   (__attribute__((address_space(3))) void*)(DST), 16, 0, 0)

__device__ inline unsigned short f2bf(float x) {
    union { float f; unsigned u; } a; a.f = x;
    unsigned r = a.u + 0x7FFFu + ((a.u >> 16) & 1u);
    return (unsigned short)(r >> 16);
}
__device__ inline float bf2f(unsigned short u) {
    union { float f; unsigned v; } a; a.v = ((unsigned)u) << 16;
    return a.f;
}

// ---------------------------------------------------------------------------
__global__ void zero_counts(int* counts) {
    if (threadIdx.x < 8) counts[threadIdx.x] = 0;
}

// ---------------------------------------------------------------------------
// Pack fp32 rows -> [rows][K/32][64] bf16 (32 hi | 32 lo per k-group).
__global__ __launch_bounds__(256)
void pack_rows(const float* __restrict__ in, unsigned short* __restrict__ out, int K)
{
    const size_t base = ((size_t)blockIdx.x * 256 + threadIdx.x) * 8;
    const size_t row = base / (size_t)K;
    const int col = (int)(base % (size_t)K);
    const float4 v0 = *(const float4*)&in[base];
    const float4 v1 = *(const float4*)&in[base + 4];
    float v[8] = {v0.x, v0.y, v0.z, v0.w, v1.x, v1.y, v1.z, v1.w};
    ush8 hv, lv;
#pragma unroll
    for (int j = 0; j < 8; ++j) {
        unsigned short hi = f2bf(v[j]);
        hv[j] = hi;
        lv[j] = f2bf(v[j] - bf2f(hi));
    }
    const size_t ob = ((size_t)row * (K >> 5) + (col >> 5)) * 64 + (col & 31);
    *(ush8*)&out[ob] = hv;
    *(ush8*)&out[ob + 32] = lv;
}

// ---------------------------------------------------------------------------
// Transposing converter: in [K][N] fp32 (batch z) -> out:
//   PACKED: [N][K/32][64] bf16 hi|lo ; else: [N][K] bf16.
template<bool PACKED>
__global__ __launch_bounds__(256)
void tconv_kernel(const float* __restrict__ in, unsigned short* __restrict__ out,
                  int K, int N)
{
    __shared__ float tile[32][33];
    const int kt = blockIdx.x, nt = blockIdx.y;
    const size_t inB = (size_t)blockIdx.z * K * N;
    const int t = threadIdx.x;
    const int lr = t >> 5, lc = t & 31;
#pragma unroll
    for (int i = 0; i < 4; ++i) {
        const int k = kt * 32 + lr + i * 8;
        tile[lr + i * 8][lc] = in[inB + (size_t)k * N + nt * 32 + lc];
    }
    __syncthreads();
    const int n_loc = t >> 3, s = t & 7;
    const int n = nt * 32 + n_loc;
    if (PACKED) {
        const size_t ob = (size_t)blockIdx.z * N * K * 2 +
                          ((size_t)n * (K >> 5) + kt) * 64;
        ush4 hv, lv;
#pragma unroll
        for (int j = 0; j < 4; ++j) {
            const float v = tile[s * 4 + j][n_loc];
            unsigned short hi = f2bf(v);
            hv[j] = hi;
            lv[j] = f2bf(v - bf2f(hi));
        }
        *(ush4*)&out[ob + s * 4] = hv;
        *(ush4*)&out[ob + 32 + s * 4] = lv;
    } else {
        const size_t ob = (size_t)blockIdx.z * N * K + (size_t)n * K + kt * 32;
        ush4 hv;
#pragma unroll
        for (int j = 0; j < 4; ++j) hv[j] = f2bf(tile[s * 4 + j][n_loc]);
        *(ush4*)&out[ob + s * 4] = hv;
    }
}

// ---------------------------------------------------------------------------
// Split-bf16 3-term GEMM: out = A[M,K] @ W[K,N] with A,B in packed hi/lo form
// (A: [M][K/32][64], Bpk: [N][K/32][64] i.e. W^T packed).
// EPI 0: BN+ReLU, write packed hi/lo bf16 (for GEMM1 -> h).
// EPI 1: +bias, write fp32.
template<int BM, int BN, int EPI>
__global__ __launch_bounds__(256)
void gemm_split3(const unsigned short* __restrict__ Apk,
                 const unsigned short* __restrict__ Bpk,
                 const float* __restrict__ bias,
                 const float* __restrict__ g, const float* __restrict__ bt,
                 const float* __restrict__ mean, const float* __restrict__ var,
                 void* __restrict__ outp, int K, int N)
{
    constexpr int WM = BM / 2, WN = BN / 2, FM = WM / 16, FN = WN / 16;
    constexpr int ROWS = BM + BN, TI = ROWS / 8, PW = TI / 4;
    __shared__ __align__(16) unsigned short lds[ROWS * 64];
    const int tid = threadIdx.x, waveId = tid >> 6, lane = tid & 63;
    const int aRowBase = blockIdx.y * BM, bColBase = blockIdx.x * BN;
    const int wRow = (waveId >> 1) * WM, wCol = (waveId & 1) * WN;
    const int Kg = K >> 5;
    const int sr = lane >> 3, ss = lane & 7;

    f32x4 acc[FM][FN] = {};

    for (int kg = 0; kg < Kg; ++kg) {
#pragma unroll
        for (int t = 0; t < PW; ++t) {
            const int q = waveId * PW + t;
            const int r = q * 8 + sr;
            const int c = ss ^ (r & 7);
            const unsigned short* src;
            if (r < BM) src = Apk + ((size_t)(aRowBase + r) * Kg + kg) * 64 + c * 8;
            else        src = Bpk + ((size_t)(bColBase + (r - BM)) * Kg + kg) * 64 + c * 8;
            GLD_LDS16(src, &lds[q * 512]);
        }
        __syncthreads();
        short8v a_hi[FM], a_lo[FM], b_hi[FN], b_lo[FN];
#pragma unroll
        for (int fm = 0; fm < FM; ++fm) {
            const int r = wRow + fm * 16 + (lane & 15);
            const int ch = lane >> 4;
            a_hi[fm] = *(const short8v*)&lds[r * 64 + ((ch) ^ (r & 7)) * 8];
            a_lo[fm] = *(const short8v*)&lds[r * 64 + ((ch + 4) ^ (r & 7)) * 8];
        }
#pragma unroll
        for (int fn = 0; fn < FN; ++fn) {
            const int r = BM + wCol + fn * 16 + (lane & 15);
            const int ch = lane >> 4;
            b_hi[fn] = *(const short8v*)&lds[r * 64 + ((ch) ^ (r & 7)) * 8];
            b_lo[fn] = *(const short8v*)&lds[r * 64 + ((ch + 4) ^ (r & 7)) * 8];
        }
#pragma unroll
        for (int fm = 0; fm < FM; ++fm)
#pragma unroll
            for (int fn = 0; fn < FN; ++fn) {
                acc[fm][fn] = MFMA16(a_hi[fm], b_hi[fn], acc[fm][fn]);
                acc[fm][fn] = MFMA16(a_hi[fm], b_lo[fn], acc[fm][fn]);
                acc[fm][fn] = MFMA16(a_lo[fm], b_hi[fn], acc[fm][fn]);
            }
        __syncthreads();
    }

#pragma unroll
    for (int fn = 0; fn < FN; ++fn) {
        const int col = bColBase + wCol + fn * 16 + (lane & 15);
        const float bcol = bias[col];
        float scl = 0.f, sft = 0.f;
        if constexpr (EPI == 0) {
            scl = rsqrtf(var[col] + EPS_BN) * g[col];
            sft = bt[col] - mean[col] * scl;
        }
#pragma unroll
        for (int fm = 0; fm < FM; ++fm)
#pragma unroll
            for (int reg = 0; reg < 4; ++reg) {
                const int row = aRowBase + wRow + fm * 16 + (lane >> 4) * 4 + reg;
                float v = acc[fm][fn][reg] + bcol;
                if constexpr (EPI == 0) {
                    v = fmaxf(v * scl + sft, 0.f);
                    unsigned short hi = f2bf(v);
                    unsigned short lo = f2bf(v - bf2f(hi));
                    unsigned short* o = (unsigned short*)outp;
                    const size_t idx = ((size_t)row * (N >> 5) + (col >> 5)) * 64 + (col & 31);
                    o[idx] = hi; o[idx + 32] = lo;
                } else {
                    ((float*)outp)[(size_t)row * N + col] = v;
                }
            }
    }
}

// ---------------------------------------------------------------------------
// 1-term bf16 expert GEMM over compacted rows (BK=64, plain bf16 rows).
// EPI 2: BN+ReLU -> bf16 out. EPI 3: +bias -> fp32 out.
template<int BM, int BN, int EPI>
__global__ __launch_bounds__(256)
void gemm_plain1(const unsigned short* __restrict__ Ab,
                 const unsigned short* __restrict__ Bt_,
                 const float* __restrict__ bias,
                 const float* __restrict__ g, const float* __restrict__ bt,
                 const float* __restrict__ mean, const float* __restrict__ var,
                 void* __restrict__ outp, const int* __restrict__ counts,
                 const int* __restrict__ offsets, int K, int N)
{
    constexpr int WM = BM / 2, WN = BN / 2, FM = WM / 16, FN = WN / 16;
    constexpr int ROWS = BM + BN, TI = ROWS / 8, PW = TI / 4;
    const int e = blockIdx.z;
    const int cnt = counts[e];
    const int aRowBase = blockIdx.y * BM;
    if (aRowBase >= cnt) return;
    const int obase = offsets[e];
    __shared__ __align__(16) unsigned short lds[ROWS * 64];
    const int tid = threadIdx.x, waveId = tid >> 6, lane = tid & 63;
    const int bColBase = blockIdx.x * BN;
    const int wRow = (waveId >> 1) * WM, wCol = (waveId & 1) * WN;
    const unsigned short* A = Ab + (size_t)obase * K;
    const unsigned short* Bp = Bt_ + (size_t)e * N * K;
    const int sr = lane >> 3, ss = lane & 7;

    f32x4 acc[FM][FN] = {};

    for (int k0 = 0; k0 < K; k0 += 64) {
#pragma unroll
        for (int t = 0; t < PW; ++t) {
            const int q = waveId * PW + t;
            const int r = q * 8 + sr;
            const int c = ss ^ (r & 7);
            const unsigned short* src;
            if (r < BM) src = A + (size_t)(aRowBase + r) * K + k0 + c * 8;
            else        src = Bp + (size_t)(bColBase + (r - BM)) * K + k0 + c * 8;
            GLD_LDS16(src, &lds[q * 512]);
        }
        __syncthreads();
#pragma unroll
        for (int ks = 0; ks < 2; ++ks) {
            short8v a[FM], b[FN];
#pragma unroll
            for (int fm = 0; fm < FM; ++fm) {
                const int r = wRow + fm * 16 + (lane & 15);
                const int c = (ks * 4 + (lane >> 4)) ^ (r & 7);
                a[fm] = *(const short8v*)&lds[r * 64 + c * 8];
            }
#pragma unroll
            for (int fn = 0; fn < FN; ++fn) {
                const int r = BM + wCol + fn * 16 + (lane & 15);
                const int c = (ks * 4 + (lane >> 4)) ^ (r & 7);
                b[fn] = *(const short8v*)&lds[r * 64 + c * 8];
            }
#pragma unroll
            for (int fm = 0; fm < FM; ++fm)
#pragma unroll
                for (int fn = 0; fn < FN; ++fn)
                    acc[fm][fn] = MFMA16(a[fm], b[fn], acc[fm][fn]);
        }
        __syncthreads();
    }

#pragma unroll
    for (int fn = 0; fn < FN; ++fn) {
        const int col = bColBase + wCol + fn * 16 + (lane & 15);
        const float bcol = bias[(size_t)e * N + col];
        float scl = 0.f, sft = 0.f;
        if constexpr (EPI == 2) {
            scl = rsqrtf(var[(size_t)e * N + col] + EPS_BN) * g[(size_t)e * N + col];
            sft = bt[(size_t)e * N + col] - mean[(size_t)e * N + col] * scl;
        }
#pragma unroll
        for (int fm = 0; fm < FM; ++fm)
#pragma unroll
            for (int reg = 0; reg < 4; ++reg) {
                const int gr = aRowBase + wRow + fm * 16 + (lane >> 4) * 4 + reg;
                if (gr < cnt) {
                    float v = acc[fm][fn][reg] + bcol;
                    if constexpr (EPI == 2) {
                        v = fmaxf(v * scl + sft, 0.f);
                        ((unsigned short*)outp)[(size_t)(obase + gr) * N + col] = f2bf(v);
                    } else {
                        ((float*)outp)[(size_t)(obase + gr) * N + col] = v;
                    }
                }
            }
    }
}

// ---------------------------------------------------------------------------
// Round-1 fp32 GEMM (kept for the refine path).
template<bool BN_RELU>
__global__ __launch_bounds__(256)
void gemm_kernel(const float* __restrict__ A, const float* __restrict__ W,
                 const float* __restrict__ bias,
                 const float* __restrict__ g, const float* __restrict__ bt,
                 const float* __restrict__ mean, const float* __restrict__ var,
                 float* __restrict__ Cout, int M, int N, int K)
{
    constexpr int BM = 64, BN = 64, BK = 16, TM = 4, TN = 4;
    __shared__ float As[BK][BM + 4];
    __shared__ float Ws[BK][BN + 4];
    const int tid = threadIdx.y * 16 + threadIdx.x;
    const int rowBase = blockIdx.y * BM;
    const int colBase = blockIdx.x * BN;
    const int aRow = tid >> 2, aCol = (tid & 3) * 4;
    const int wRow = tid >> 4, wCol = (tid & 15) * 4;
    float acc[TM][TN] = {};

    for (int k0 = 0; k0 < K; k0 += BK) {
        const float4 av = *reinterpret_cast<const float4*>(
            &A[(size_t)(rowBase + aRow) * K + k0 + aCol]);
        As[aCol + 0][aRow] = av.x; As[aCol + 1][aRow] = av.y;
        As[aCol + 2][aRow] = av.z; As[aCol + 3][aRow] = av.w;
        const float4 wv = *reinterpret_cast<const float4*>(
            &W[(size_t)(k0 + wRow) * N + colBase + wCol]);
        *reinterpret_cast<float4*>(&Ws[wRow][wCol]) = wv;
        __syncthreads();
#pragma unroll
        for (int kk = 0; kk < BK; ++kk) {
            float a[TM], w[TN];
#pragma unroll
            for (int i = 0; i < TM; ++i) a[i] = As[kk][threadIdx.y * TM + i];
#pragma unroll
            for (int j = 0; j < TN; ++j) w[j] = Ws[kk][threadIdx.x * TN + j];
#pragma unroll
            for (int i = 0; i < TM; ++i)
#pragma unroll
                for (int j = 0; j < TN; ++j)
                    acc[i][j] = fmaf(a[i], w[j], acc[i][j]);
        }
        __syncthreads();
    }
#pragma unroll
    for (int i = 0; i < TM; ++i) {
        const int row = rowBase + threadIdx.y * TM + i;
#pragma unroll
        for (int j = 0; j < TN; ++j) {
            const int col = colBase + threadIdx.x * TN + j;
            float v = acc[i][j] + bias[col];
            if constexpr (BN_RELU) {
                v = (v - mean[col]) * rsqrtf(var[col] + EPS_BN) * g[col] + bt[col];
                v = fmaxf(v, 0.f);
            }
            Cout[(size_t)row * N + col] = v;
        }
    }
}

// Refine GEMM1: gathered fp32 rows (flagged), BN+ReLU, K=D_, N=H_.
__global__ __launch_bounds__(256)
void refine_gemm1(const float* __restrict__ feats, const float* __restrict__ W,
                  const float* __restrict__ bias, const float* __restrict__ g,
                  const float* __restrict__ bt, const float* __restrict__ mean,
                  const float* __restrict__ var,
                  const int* __restrict__ rlist, const int* __restrict__ counts,
                  float* __restrict__ outp)
{
    constexpr int BM = 64, BN = 64, BK = 16, TM = 4, TN = 4;
    const int cnt_raw = counts[5];
    const int cnt = cnt_raw > RMAX ? RMAX : cnt_raw;
    const int rowTile = blockIdx.y * BM;
    if (rowTile >= cnt) return;
    __shared__ float As[BK][BM + 4];
    __shared__ float Ws[BK][BN + 4];
    const int tid = threadIdx.y * 16 + threadIdx.x;
    const int colBase = blockIdx.x * BN;
    const int aRow = tid >> 2, aCol = (tid & 3) * 4;
    const int wRow = tid >> 4, wCol = (tid & 15) * 4;
    const int gi = rowTile + aRow;
    const int srcRow = (gi < cnt) ? rlist[gi] : 0;
    float acc[TM][TN] = {};

    for (int k0 = 0; k0 < D_; k0 += BK) {
        const float4 av = *reinterpret_cast<const float4*>(
            &feats[(size_t)srcRow * D_ + k0 + aCol]);
        As[aCol + 0][aRow] = av.x; As[aCol + 1][aRow] = av.y;
        As[aCol + 2][aRow] = av.z; As[aCol + 3][aRow] = av.w;
        const float4 wv = *reinterpret_cast<const float4*>(
            &W[(size_t)(k0 + wRow) * H_ + colBase + wCol]);
        *reinterpret_cast<float4*>(&Ws[wRow][wCol]) = wv;
        __syncthreads();
#pragma unroll
        for (int kk = 0; kk < BK; ++kk) {
            float a[TM], w[TN];
#pragma unroll
            for (int i = 0; i < TM; ++i) a[i] = As[kk][threadIdx.y * TM + i];
#pragma unroll
            for (int j = 0; j < TN; ++j) w[j] = Ws[kk][threadIdx.x * TN + j];
#pragma unroll
            for (int i = 0; i < TM; ++i)
#pragma unroll
                for (int j = 0; j < TN; ++j)
                    acc[i][j] = fmaf(a[i], w[j], acc[i][j]);
        }
        __syncthreads();
    }
#pragma unroll
    for (int i = 0; i < TM; ++i) {
        const int gr = rowTile + threadIdx.y * TM + i;
        if (gr >= cnt) continue;
#pragma unroll
        for (int j = 0; j < TN; ++j) {
            const int col = colBase + threadIdx.x * TN + j;
            float v = acc[i][j] + bias[col];
            v = (v - mean[col]) * rsqrtf(var[col] + EPS_BN) * g[col] + bt[col];
            outp[(size_t)gr * H_ + col] = fmaxf(v, 0.f);
        }
    }
}

// ---------------------------------------------------------------------------
__global__ __launch_bounds__(256)
void norm_rows(const float* __restrict__ in, float* __restrict__ ws_zp,
               float* __restrict__ out_zp)
{
    const int row = blockIdx.x, t = threadIdx.x;
    const float v = in[(size_t)row * Z_ + t];
    float s = v * v;
    for (int off = 32; off; off >>= 1) s += __shfl_down(s, off);
    __shared__ float wsum[4];
    if ((t & 63) == 0) wsum[t >> 6] = s;
    __syncthreads();
    const float tot = wsum[0] + wsum[1] + wsum[2] + wsum[3];
    const float scale = 1.f / fmaxf(sqrtf(tot), EPS_NORM);
    const float z = v * scale;
    ws_zp[(size_t)row * Z_ + t] = z;
    out_zp[(size_t)row * Z_ + t] = z;
}

// Pattern logits + flag near-tied rows for exact recompute.
__global__ __launch_bounds__(256)
void logits_flag(const float* __restrict__ zp, const float* __restrict__ pProto,
                 float* __restrict__ out_lp, int* __restrict__ counts,
                 int* __restrict__ rlist)
{
    const int wave = threadIdx.x >> 6, lane = threadIdx.x & 63;
    const int b = blockIdx.x * 4 + wave;
    const float4 z = *(const float4*)&zp[(size_t)b * Z_ + lane * 4];
    float p[E_];
#pragma unroll
    for (int e = 0; e < E_; ++e) {
        const float4 pr = *(const float4*)&pProto[(size_t)e * Z_ + lane * 4];
        float s = z.x * pr.x + z.y * pr.y + z.z * pr.z + z.w * pr.w;
        for (int off = 32; off; off >>= 1) s += __shfl_down(s, off);
        p[e] = s;
    }
    if (lane == 0) {
        float b1 = -1e30f, b2 = -1e30f;
#pragma unroll
        for (int e = 0; e < E_; ++e) {
            out_lp[(size_t)b * E_ + e] = p[e];
            if (p[e] > b1) { b2 = b1; b1 = p[e]; }
            else if (p[e] > b2) b2 = p[e];
        }
        if (b1 - b2 < GAP_TAU) {
            const int i = atomicAdd(&counts[5], 1);
            if (i < RMAX) rlist[i] = b;
        }
    }
}

// Refine finalize: normalize refined row, recompute 5 logits, overwrite out_lp.
__global__ __launch_bounds__(256)
void refine_finalize(const float* __restrict__ tR, const float* __restrict__ pProto,
                     const int* __restrict__ rlist, const int* __restrict__ counts,
                     float* __restrict__ out_lp)
{
    const int cnt_raw = counts[5];
    const int cnt = cnt_raw > RMAX ? RMAX : cnt_raw;
    const int i = blockIdx.x;
    if (i >= cnt) return;
    const int b = rlist[i];
    const int t = threadIdx.x;
    const float v = tR[(size_t)i * Z_ + t];
    __shared__ float wsum[4];
    float s = v * v;
    for (int off = 32; off; off >>= 1) s += __shfl_down(s, off);
    if ((t & 63) == 0) wsum[t >> 6] = s;
    __syncthreads();
    const float scale = 1.f / fmaxf(sqrtf(wsum[0] + wsum[1] + wsum[2] + wsum[3]), EPS_NORM);
    const float z = v * scale;
    for (int e = 0; e < E_; ++e) {
        float d = z * pProto[(size_t)e * Z_ + t];
        for (int off = 32; off; off >>= 1) d += __shfl_down(d, off);
        __syncthreads();
        if ((t & 63) == 0) wsum[t >> 6] = d;
        __syncthreads();
        if (t == 0) out_lp[(size_t)b * E_ + e] = wsum[0] + wsum[1] + wsum[2] + wsum[3];
    }
}

// Final routing from (possibly refined) logits.
__global__ __launch_bounds__(256)
void route_kernel(const float* __restrict__ lp, int* __restrict__ counts,
                  int* __restrict__ lists)
{
    const int b = blockIdx.x * 256 + threadIdx.x;
    const float* p = lp + (size_t)b * E_;
    int best = 0; float bv = p[0];
#pragma unroll
    for (int e = 1; e < E_; ++e) { const float x = p[e]; if (x > bv) { bv = x; best = e; } }
    const int pos = atomicAdd(&counts[best], 1);
    lists[best * B_ + pos] = b;
}

__global__ void calc_offsets(const int* __restrict__ counts, int* __restrict__ offsets) {
    if (threadIdx.x == 0) {
        int acc = 0;
        for (int e = 0; e < E_; ++e) { offsets[e] = acc; acc += counts[e]; }
        offsets[E_] = acc;
    }
}

// Gather zp rows into compact order, converting to bf16.
__global__ __launch_bounds__(64)
void gather_zpc(const float* __restrict__ zp, const int* __restrict__ lists,
                const int* __restrict__ offsets, unsigned short* __restrict__ zpc)
{
    const int c = blockIdx.x;
    int e = 0;
#pragma unroll
    for (int k = 1; k < E_; ++k) if (c >= offsets[k]) e = k;
    const int b = lists[e * B_ + (c - offsets[e])];
    const int t = threadIdx.x;
    const float4 v = *(const float4*)&zp[(size_t)b * Z_ + t * 4];
    ush4 o = { f2bf(v.x), f2bf(v.y), f2bf(v.z), f2bf(v.w) };
    *(ush4*)&zpc[(size_t)c * Z_ + t * 4] = o;
}

// ---------------------------------------------------------------------------
__global__ __launch_bounds__(256)
void finalize(const float* __restrict__ z2c, const float* __restrict__ cProto,
              const int* __restrict__ lists, const int* __restrict__ offsets,
              float* __restrict__ out_lc, float* __restrict__ out_pf)
{
    const int c = blockIdx.x;
    const int t = threadIdx.x;
    int e = 0;
#pragma unroll
    for (int k = 1; k < E_; ++k) if (c >= offsets[k]) e = k;
    const int b = lists[e * B_ + (c - offsets[e])];

    const float v = z2c[(size_t)c * Z_ + t];
    float s = v * v;
    for (int off = 32; off; off >>= 1) s += __shfl_down(s, off);
    __shared__ float wsum[4];
    if ((t & 63) == 0) wsum[t >> 6] = s;
    __syncthreads();
    const float tot = wsum[0] + wsum[1] + wsum[2] + wsum[3];
    const float scale = 1.f / fmaxf(sqrtf(tot), EPS_NORM);
    const float z = v * scale;
    out_pf[(size_t)b * Z_ + t] = z;

    __shared__ float zn[Z_];
    zn[t] = z;
    __syncthreads();
    if (t < C_) {
        const float* pr = &cProto[((size_t)e * C_ + t) * Z_];
        float acc = 0.f;
        for (int zi = 0; zi < Z_; ++zi) acc = fmaf(zn[zi], pr[zi], acc);
        out_lc[(size_t)b * C_ + t] = acc;
    }
}

// ---------------------------------------------------------------------------
extern "C" void kernel_launch(void* const* d_in, const int* in_sizes, int n_in,
                              void* d_out, int out_size, void* d_ws, size_t ws_size,
                              hipStream_t stream)
{
    const float* feats  = (const float*)d_in[0];
    const float* pW1    = (const float*)d_in[1];
    const float* pb1    = (const float*)d_in[2];
    const float* pg     = (const float*)d_in[3];
    const float* pbt    = (const float*)d_in[4];
    const float* pm     = (const float*)d_in[5];
    const float* pv     = (const float*)d_in[6];
    const float* pW2    = (const float*)d_in[7];
    const float* pb2    = (const float*)d_in[8];
    const float* pProto = (const float*)d_in[9];
    const float* cW1    = (const float*)d_in[10];
    const float* cb1    = (const float*)d_in[11];
    const float* cg     = (const float*)d_in[12];
    const float* cbt    = (const float*)d_in[13];
    const float* cm     = (const float*)d_in[14];
    const float* cv     = (const float*)d_in[15];
    const float* cW2    = (const float*)d_in[16];
    const float* cb2    = (const float*)d_in[17];
    const float* cProto = (const float*)d_in[18];

    // workspace layout (ushort units unless noted)
    unsigned short* fAp  = (unsigned short*)d_ws;                 // B*D*2   = 33,554,432
    unsigned short* hpk  = fAp  + (size_t)B_ * D_ * 2;            // B*H*2   = 33,554,432
    unsigned short* W1Tp = hpk  + (size_t)B_ * H_ * 2;            // H*D*2   = 8,388,608
    unsigned short* W2Tp = W1Tp + (size_t)H_ * D_ * 2;            // Z*H*2   = 1,048,576
    unsigned short* cW1T = W2Tp + (size_t)Z_ * H_ * 2;            // E*H*Z   = 2,621,440
    unsigned short* cW2T = cW1T + (size_t)E_ * H_ * Z_;           // E*Z*H   = 2,621,440
    unsigned short* zpc  = cW2T + (size_t)E_ * Z_ * H_;           // (B+128)*Z = 2,129,920
    float* zp  = (float*)(zpc + (size_t)(B_ + 128) * Z_);         // B*Z floats
    float* z2c = zp + (size_t)B_ * Z_;                            // (B+128)*Z floats
    int* counts  = (int*)(z2c + (size_t)(B_ + 128) * Z_);
    int* offsets = counts + 8;
    int* rlist   = offsets + 8;
    int* lists   = rlist + RMAX;
    // reused regions:
    unsigned short* h2c = fAp;              // after GEMM1, (B+128)*H bf16
    float* hR = (float*)hpk;                // after GEMM2, RMAX*H fp32
    float* tR = hR + (size_t)RMAX * H_;     // RMAX*Z fp32

    float* out_lp = (float*)d_out;
    float* out_zp = out_lp + (size_t)B_ * E_;
    float* out_lc = out_zp + (size_t)B_ * Z_;
    float* out_pf = out_lc + (size_t)B_ * C_;

    zero_counts<<<1, 64, 0, stream>>>(counts);

    // convert / pack
    pack_rows<<<(int)(((size_t)B_ * D_) / 2048), 256, 0, stream>>>(feats, fAp, D_);
    tconv_kernel<true ><<<dim3(D_ / 32, H_ / 32, 1), 256, 0, stream>>>(pW1, W1Tp, D_, H_);
    tconv_kernel<true ><<<dim3(H_ / 32, Z_ / 32, 1), 256, 0, stream>>>(pW2, W2Tp, H_, Z_);
    tconv_kernel<false><<<dim3(Z_ / 32, H_ / 32, E_), 256, 0, stream>>>(cW1, cW1T, Z_, H_);
    tconv_kernel<false><<<dim3(H_ / 32, Z_ / 32, E_), 256, 0, stream>>>(cW2, cW2T, H_, Z_);

    // pattern head (3-term split bf16 MFMA)
    gemm_split3<128, 128, 0><<<dim3(H_ / 128, B_ / 128), 256, 0, stream>>>(
        fAp, W1Tp, pb1, pg, pbt, pm, pv, hpk, D_, H_);
    gemm_split3<128, 64, 1><<<dim3(Z_ / 64, B_ / 128), 256, 0, stream>>>(
        hpk, W2Tp, pb2, nullptr, nullptr, nullptr, nullptr, zp, H_, Z_);

    norm_rows<<<B_, 256, 0, stream>>>(zp, zp, out_zp);
    logits_flag<<<B_ / 4, 256, 0, stream>>>(zp, pProto, out_lp, counts, rlist);

    // exact fp32 recompute for near-tied rows
    refine_gemm1<<<dim3(H_ / 64, RMAX / 64), dim3(16, 16), 0, stream>>>(
        feats, pW1, pb1, pg, pbt, pm, pv, rlist, counts, hR);
    gemm_kernel<false><<<dim3(Z_ / 64, RMAX / 64), dim3(16, 16), 0, stream>>>(
        hR, pW2, pb2, nullptr, nullptr, nullptr, nullptr, tR, RMAX, Z_, H_);
    refine_finalize<<<RMAX, 256, 0, stream>>>(tR, pProto, rlist, counts, out_lp);

    // routing + compaction
    route_kernel<<<B_ / 256, 256, 0, stream>>>(out_lp, counts, lists);
    calc_offsets<<<1, 64, 0, stream>>>(counts, offsets);
    gather_zpc<<<B_, 64, 0, stream>>>(zp, lists, offsets, zpc);

    // experts (1-term bf16 MFMA over compacted rows)
    gemm_plain1<128, 128, 2><<<dim3(H_ / 128, B_ / 128, E_), 256, 0, stream>>>(
        zpc, cW1T, cb1, cg, cbt, cm, cv, h2c, counts, offsets, Z_, H_);
    gemm_plain1<128, 128, 3><<<dim3(Z_ / 128, B_ / 128, E_), 256, 0, stream>>>(
        h2c, cW2T, cb2, nullptr, nullptr, nullptr, nullptr, z2c, counts, offsets, H_, Z_);

    finalize<<<B_, 256, 0, stream>>>(z2c, cProto, lists, offsets, out_lc, out_pf);
}

// Round 5
// 842.907 us; speedup vs baseline: 2.1447x; 1.0942x over previous
//
#include <hip/hip_runtime.h>
#include <math.h>

#define EPS_BN   1e-5f
#define EPS_NORM 1e-12f
#define GAP_TAU  1e-3f
#define RMAX     1024

constexpr int B_ = 8192, D_ = 2048, H_ = 2048, Z_ = 256, E_ = 5, C_ = 100;

typedef __attribute__((ext_vector_type(8))) short short8v;
typedef __attribute__((ext_vector_type(4))) float f32x4;
typedef __attribute__((ext_vector_type(8))) unsigned short ush8;
typedef __attribute__((ext_vector_type(4))) unsigned short ush4;

#define MFMA16(a,b,c) __builtin_amdgcn_mfma_f32_16x16x32_bf16(a,b,c,0,0,0)

#define GLD_LDS16(SRC, DST) \
  __builtin_amdgcn_global_load_lds((const __attribute__((address_space(1))) void*)(SRC), \
                                   (__attribute__((address_space(3))) void*)(DST), 16, 0, 0)

__device__ inline unsigned short f2bf(float x) {
    union { float f; unsigned u; } a; a.f = x;
    unsigned r = a.u + 0x7FFFu + ((a.u >> 16) & 1u);
    return (unsigned short)(r >> 16);
}
__device__ inline float bf2f(unsigned short u) {
    union { float f; unsigned v; } a; a.v = ((unsigned)u) << 16;
    return a.f;
}

// ---------------------------------------------------------------------------
// Pack fp32 rows -> [rows][K/32][64] bf16 (32 hi | 32 lo per k-group).
// Also zeroes the routing counters (block 0).
__global__ __launch_bounds__(256)
void pack_rows(const float* __restrict__ in, unsigned short* __restrict__ out,
               int K, int* __restrict__ counts)
{
    if (blockIdx.x == 0 && threadIdx.x < 8) counts[threadIdx.x] = 0;
    const size_t base = ((size_t)blockIdx.x * 256 + threadIdx.x) * 8;
    const size_t row = base / (size_t)K;
    const int col = (int)(base % (size_t)K);
    const float4 v0 = *(const float4*)&in[base];
    const float4 v1 = *(const float4*)&in[base + 4];
    float v[8] = {v0.x, v0.y, v0.z, v0.w, v1.x, v1.y, v1.z, v1.w};
    ush8 hv, lv;
#pragma unroll
    for (int j = 0; j < 8; ++j) {
        unsigned short hi = f2bf(v[j]);
        hv[j] = hi;
        lv[j] = f2bf(v[j] - bf2f(hi));
    }
    const size_t ob = ((size_t)row * (K >> 5) + (col >> 5)) * 64 + (col & 31);
    *(ush8*)&out[ob] = hv;
    *(ush8*)&out[ob + 32] = lv;
}

// ---------------------------------------------------------------------------
// Transposing converter: in [K][N] fp32 (batch z) -> out:
//   PACKED: [N][K/32][64] bf16 hi|lo ; else: [N][K] bf16.
template<bool PACKED>
__global__ __launch_bounds__(256)
void tconv_kernel(const float* __restrict__ in, unsigned short* __restrict__ out,
                  int K, int N)
{
    __shared__ float tile[32][33];
    const int kt = blockIdx.x, nt = blockIdx.y;
    const size_t inB = (size_t)blockIdx.z * K * N;
    const int t = threadIdx.x;
    const int lr = t >> 5, lc = t & 31;
#pragma unroll
    for (int i = 0; i < 4; ++i) {
        const int k = kt * 32 + lr + i * 8;
        tile[lr + i * 8][lc] = in[inB + (size_t)k * N + nt * 32 + lc];
    }
    __syncthreads();
    const int n_loc = t >> 3, s = t & 7;
    const int n = nt * 32 + n_loc;
    if (PACKED) {
        const size_t ob = (size_t)blockIdx.z * N * K * 2 +
                          ((size_t)n * (K >> 5) + kt) * 64;
        ush4 hv, lv;
#pragma unroll
        for (int j = 0; j < 4; ++j) {
            const float v = tile[s * 4 + j][n_loc];
            unsigned short hi = f2bf(v);
            hv[j] = hi;
            lv[j] = f2bf(v - bf2f(hi));
        }
        *(ush4*)&out[ob + s * 4] = hv;
        *(ush4*)&out[ob + 32 + s * 4] = lv;
    } else {
        const size_t ob = (size_t)blockIdx.z * N * K + (size_t)n * K + kt * 32;
        ush4 hv;
#pragma unroll
        for (int j = 0; j < 4; ++j) hv[j] = f2bf(tile[s * 4 + j][n_loc]);
        *(ush4*)&out[ob + s * 4] = hv;
    }
}

// cProto [E][C][Z] fp32 -> [E][128][Z] bf16, rows 100..127 zero-padded.
__global__ __launch_bounds__(64)
void conv_cproto(const float* __restrict__ cProto, unsigned short* __restrict__ out)
{
    const int e = blockIdx.x >> 7, r = blockIdx.x & 127;
    const int t = threadIdx.x;
    ush4 o;
    if (r < C_) {
        const float4 v = *(const float4*)&cProto[((size_t)e * C_ + r) * Z_ + t * 4];
        o = ush4{ f2bf(v.x), f2bf(v.y), f2bf(v.z), f2bf(v.w) };
    } else {
        o = ush4{ 0, 0, 0, 0 };
    }
    *(ush4*)&out[((size_t)e * 128 + r) * Z_ + t * 4] = o;
}

// ---------------------------------------------------------------------------
// Split-bf16 3-term GEMM: out = A[M,K] @ W[K,N], A/B in packed hi/lo form.
// EPI 0: BN+ReLU, write packed hi/lo bf16. EPI 1: +bias, write fp32.
template<int BM, int BN, int EPI>
__global__ __launch_bounds__(256)
void gemm_split3(const unsigned short* __restrict__ Apk,
                 const unsigned short* __restrict__ Bpk,
                 const float* __restrict__ bias,
                 const float* __restrict__ g, const float* __restrict__ bt,
                 const float* __restrict__ mean, const float* __restrict__ var,
                 void* __restrict__ outp, int K, int N)
{
    constexpr int WM = BM / 2, WN = BN / 2, FM = WM / 16, FN = WN / 16;
    constexpr int ROWS = BM + BN, TI = ROWS / 8, PW = TI / 4;
    __shared__ __align__(16) unsigned short lds[ROWS * 64];
    const int tid = threadIdx.x, waveId = tid >> 6, lane = tid & 63;
    const int aRowBase = blockIdx.y * BM, bColBase = blockIdx.x * BN;
    const int wRow = (waveId >> 1) * WM, wCol = (waveId & 1) * WN;
    const int Kg = K >> 5;
    const int sr = lane >> 3, ss = lane & 7;

    // hoisted staging pointers (advance by 64 ushorts per k-group)
    const unsigned short* sp[PW];
#pragma unroll
    for (int t = 0; t < PW; ++t) {
        const int q = waveId * PW + t;
        const int r = q * 8 + sr;
        const int c = ss ^ (r & 7);
        sp[t] = (r < BM)
            ? Apk + ((size_t)(aRowBase + r) * Kg) * 64 + c * 8
            : Bpk + ((size_t)(bColBase + (r - BM)) * Kg) * 64 + c * 8;
    }

    f32x4 acc[FM][FN] = {};

    for (int kg = 0; kg < Kg; ++kg) {
#pragma unroll
        for (int t = 0; t < PW; ++t) {
            GLD_LDS16(sp[t], &lds[(waveId * PW + t) * 512]);
            sp[t] += 64;
        }
        __syncthreads();
        short8v a_hi[FM], a_lo[FM], b_hi[FN], b_lo[FN];
#pragma unroll
        for (int fm = 0; fm < FM; ++fm) {
            const int r = wRow + fm * 16 + (lane & 15);
            const int ch = lane >> 4;
            a_hi[fm] = *(const short8v*)&lds[r * 64 + ((ch) ^ (r & 7)) * 8];
            a_lo[fm] = *(const short8v*)&lds[r * 64 + ((ch + 4) ^ (r & 7)) * 8];
        }
#pragma unroll
        for (int fn = 0; fn < FN; ++fn) {
            const int r = BM + wCol + fn * 16 + (lane & 15);
            const int ch = lane >> 4;
            b_hi[fn] = *(const short8v*)&lds[r * 64 + ((ch) ^ (r & 7)) * 8];
            b_lo[fn] = *(const short8v*)&lds[r * 64 + ((ch + 4) ^ (r & 7)) * 8];
        }
#pragma unroll
        for (int fm = 0; fm < FM; ++fm)
#pragma unroll
            for (int fn = 0; fn < FN; ++fn) {
                acc[fm][fn] = MFMA16(a_hi[fm], b_hi[fn], acc[fm][fn]);
                acc[fm][fn] = MFMA16(a_hi[fm], b_lo[fn], acc[fm][fn]);
                acc[fm][fn] = MFMA16(a_lo[fm], b_hi[fn], acc[fm][fn]);
            }
        __syncthreads();
    }

#pragma unroll
    for (int fn = 0; fn < FN; ++fn) {
        const int col = bColBase + wCol + fn * 16 + (lane & 15);
        const float bcol = bias[col];
        float scl = 0.f, sft = 0.f;
        if constexpr (EPI == 0) {
            scl = rsqrtf(var[col] + EPS_BN) * g[col];
            sft = bt[col] - mean[col] * scl;
        }
#pragma unroll
        for (int fm = 0; fm < FM; ++fm)
#pragma unroll
            for (int reg = 0; reg < 4; ++reg) {
                const int row = aRowBase + wRow + fm * 16 + (lane >> 4) * 4 + reg;
                float v = acc[fm][fn][reg] + bcol;
                if constexpr (EPI == 0) {
                    v = fmaxf(v * scl + sft, 0.f);
                    unsigned short hi = f2bf(v);
                    unsigned short lo = f2bf(v - bf2f(hi));
                    unsigned short* o = (unsigned short*)outp;
                    const size_t idx = ((size_t)row * (N >> 5) + (col >> 5)) * 64 + (col & 31);
                    o[idx] = hi; o[idx + 32] = lo;
                } else {
                    ((float*)outp)[(size_t)row * N + col] = v;
                }
            }
    }
}

// ---------------------------------------------------------------------------
// 1-term bf16 GEMM over compacted rows (BK=64, plain bf16 [*,K] rows).
// GATHER: A-rows gathered via lists (per-expert). EPI 2: BN+ReLU -> bf16.
// EPI 3: +bias -> fp32.
template<int BM, int BN, int EPI, bool GATHER>
__global__ __launch_bounds__(256)
void gemm_plain1(const unsigned short* __restrict__ Ab,
                 const unsigned short* __restrict__ Bt_,
                 const float* __restrict__ bias,
                 const float* __restrict__ g, const float* __restrict__ bt,
                 const float* __restrict__ mean, const float* __restrict__ var,
                 void* __restrict__ outp, const int* __restrict__ counts,
                 const int* __restrict__ offsets, const int* __restrict__ lists,
                 int K, int N)
{
    constexpr int WM = BM / 2, WN = BN / 2, FM = WM / 16, FN = WN / 16;
    constexpr int ROWS = BM + BN, TI = ROWS / 8, PW = TI / 4;
    const int e = blockIdx.z;
    const int cnt = counts[e];
    const int aRowBase = blockIdx.y * BM;
    if (aRowBase >= cnt) return;
    const int obase = offsets[e];
    __shared__ __align__(16) unsigned short lds[ROWS * 64];
    const int tid = threadIdx.x, waveId = tid >> 6, lane = tid & 63;
    const int bColBase = blockIdx.x * BN;
    const int wRow = (waveId >> 1) * WM, wCol = (waveId & 1) * WN;
    const unsigned short* Bp = Bt_ + (size_t)e * N * K;
    const int sr = lane >> 3, ss = lane & 7;

    const unsigned short* sp[PW];
#pragma unroll
    for (int t = 0; t < PW; ++t) {
        const int q = waveId * PW + t;
        const int r = q * 8 + sr;
        const int c = ss ^ (r & 7);
        if (r < BM) {
            int gi = aRowBase + r;
            if constexpr (GATHER) {
                const int srcb = lists[e * B_ + (gi < cnt ? gi : cnt - 1)];
                sp[t] = Ab + (size_t)srcb * K + c * 8;
            } else {
                sp[t] = Ab + (size_t)(obase + gi) * K + c * 8;
            }
        } else {
            sp[t] = Bp + (size_t)(bColBase + (r - BM)) * K + c * 8;
        }
    }

    f32x4 acc[FM][FN] = {};

    for (int k0 = 0; k0 < K; k0 += 64) {
#pragma unroll
        for (int t = 0; t < PW; ++t) {
            GLD_LDS16(sp[t], &lds[(waveId * PW + t) * 512]);
            sp[t] += 64;
        }
        __syncthreads();
#pragma unroll
        for (int ks = 0; ks < 2; ++ks) {
            short8v a[FM], b[FN];
#pragma unroll
            for (int fm = 0; fm < FM; ++fm) {
                const int r = wRow + fm * 16 + (lane & 15);
                const int c = (ks * 4 + (lane >> 4)) ^ (r & 7);
                a[fm] = *(const short8v*)&lds[r * 64 + c * 8];
            }
#pragma unroll
            for (int fn = 0; fn < FN; ++fn) {
                const int r = BM + wCol + fn * 16 + (lane & 15);
                const int c = (ks * 4 + (lane >> 4)) ^ (r & 7);
                b[fn] = *(const short8v*)&lds[r * 64 + c * 8];
            }
#pragma unroll
            for (int fm = 0; fm < FM; ++fm)
#pragma unroll
                for (int fn = 0; fn < FN; ++fn)
                    acc[fm][fn] = MFMA16(a[fm], b[fn], acc[fm][fn]);
        }
        __syncthreads();
    }

#pragma unroll
    for (int fn = 0; fn < FN; ++fn) {
        const int col = bColBase + wCol + fn * 16 + (lane & 15);
        const float bcol = bias[(size_t)e * N + col];
        float scl = 0.f, sft = 0.f;
        if constexpr (EPI == 2) {
            scl = rsqrtf(var[(size_t)e * N + col] + EPS_BN) * g[(size_t)e * N + col];
            sft = bt[(size_t)e * N + col] - mean[(size_t)e * N + col] * scl;
        }
#pragma unroll
        for (int fm = 0; fm < FM; ++fm)
#pragma unroll
            for (int reg = 0; reg < 4; ++reg) {
                const int gr = aRowBase + wRow + fm * 16 + (lane >> 4) * 4 + reg;
                if (gr < cnt) {
                    float v = acc[fm][fn][reg] + bcol;
                    if constexpr (EPI == 2) {
                        v = fmaxf(v * scl + sft, 0.f);
                        ((unsigned short*)outp)[(size_t)(obase + gr) * N + col] = f2bf(v);
                    } else {
                        ((float*)outp)[(size_t)(obase + gr) * N + col] = v;
                    }
                }
            }
    }
}

// ---------------------------------------------------------------------------
// Per-expert class-logits GEMM: lc = z2nb[cnt,256] @ cProtoB[e][128,256]^T,
// scatter rows to out_lc via lists; only cols < C_ written.
__global__ __launch_bounds__(256)
void class_gemm(const unsigned short* __restrict__ Ab,
                const unsigned short* __restrict__ Bt_,
                const int* __restrict__ counts, const int* __restrict__ offsets,
                const int* __restrict__ lists, float* __restrict__ out_lc)
{
    constexpr int BM = 128, BN = 128, FM = 4, FN = 4;
    constexpr int ROWS = BM + BN, PW = (ROWS / 8) / 4;
    constexpr int K = Z_;
    const int e = blockIdx.z;
    const int cnt = counts[e];
    const int aRowBase = blockIdx.y * BM;
    if (aRowBase >= cnt) return;
    const int obase = offsets[e];
    __shared__ __align__(16) unsigned short lds[ROWS * 64];
    const int tid = threadIdx.x, waveId = tid >> 6, lane = tid & 63;
    const int wRow = (waveId >> 1) * 64, wCol = (waveId & 1) * 64;
    const unsigned short* Bp = Bt_ + (size_t)e * 128 * K;
    const int sr = lane >> 3, ss = lane & 7;

    const unsigned short* sp[PW];
#pragma unroll
    for (int t = 0; t < PW; ++t) {
        const int q = waveId * PW + t;
        const int r = q * 8 + sr;
        const int c = ss ^ (r & 7);
        sp[t] = (r < BM) ? Ab + (size_t)(obase + aRowBase + r) * K + c * 8
                         : Bp + (size_t)(r - BM) * K + c * 8;
    }

    f32x4 acc[FM][FN] = {};

    for (int k0 = 0; k0 < K; k0 += 64) {
#pragma unroll
        for (int t = 0; t < PW; ++t) {
            GLD_LDS16(sp[t], &lds[(waveId * PW + t) * 512]);
            sp[t] += 64;
        }
        __syncthreads();
#pragma unroll
        for (int ks = 0; ks < 2; ++ks) {
            short8v a[FM], b[FN];
#pragma unroll
            for (int fm = 0; fm < FM; ++fm) {
                const int r = wRow + fm * 16 + (lane & 15);
                const int c = (ks * 4 + (lane >> 4)) ^ (r & 7);
                a[fm] = *(const short8v*)&lds[r * 64 + c * 8];
            }
#pragma unroll
            for (int fn = 0; fn < FN; ++fn) {
                const int r = BM + wCol + fn * 16 + (lane & 15);
                const int c = (ks * 4 + (lane >> 4)) ^ (r & 7);
                b[fn] = *(const short8v*)&lds[r * 64 + c * 8];
            }
#pragma unroll
            for (int fm = 0; fm < FM; ++fm)
#pragma unroll
                for (int fn = 0; fn < FN; ++fn)
                    acc[fm][fn] = MFMA16(a[fm], b[fn], acc[fm][fn]);
        }
        __syncthreads();
    }

#pragma unroll
    for (int fn = 0; fn < FN; ++fn) {
        const int col = wCol + fn * 16 + (lane & 15);
        if (col >= C_) continue;
#pragma unroll
        for (int fm = 0; fm < FM; ++fm)
#pragma unroll
            for (int reg = 0; reg < 4; ++reg) {
                const int gr = aRowBase + wRow + fm * 16 + (lane >> 4) * 4 + reg;
                if (gr < cnt) {
                    const int b = lists[e * B_ + gr];
                    out_lc[(size_t)b * C_ + col] = acc[fm][fn][reg];
                }
            }
    }
}

// ---------------------------------------------------------------------------
// Round-1 style fp32 refine GEMMs (gated by flagged count).
__global__ __launch_bounds__(256)
void refine_gemm1(const float* __restrict__ feats, const float* __restrict__ W,
                  const float* __restrict__ bias, const float* __restrict__ g,
                  const float* __restrict__ bt, const float* __restrict__ mean,
                  const float* __restrict__ var,
                  const int* __restrict__ rlist, const int* __restrict__ counts,
                  float* __restrict__ outp)
{
    constexpr int BM = 64, BN = 64, BK = 16, TM = 4, TN = 4;
    const int cnt_raw = counts[5];
    const int cnt = cnt_raw > RMAX ? RMAX : cnt_raw;
    const int rowTile = blockIdx.y * BM;
    if (rowTile >= cnt) return;
    __shared__ float As[BK][BM + 4];
    __shared__ float Ws[BK][BN + 4];
    const int tid = threadIdx.y * 16 + threadIdx.x;
    const int colBase = blockIdx.x * BN;
    const int aRow = tid >> 2, aCol = (tid & 3) * 4;
    const int wRow = tid >> 4, wCol = (tid & 15) * 4;
    const int gi = rowTile + aRow;
    const int srcRow = (gi < cnt) ? rlist[gi] : 0;
    float acc[TM][TN] = {};

    for (int k0 = 0; k0 < D_; k0 += BK) {
        const float4 av = *reinterpret_cast<const float4*>(
            &feats[(size_t)srcRow * D_ + k0 + aCol]);
        As[aCol + 0][aRow] = av.x; As[aCol + 1][aRow] = av.y;
        As[aCol + 2][aRow] = av.z; As[aCol + 3][aRow] = av.w;
        const float4 wv = *reinterpret_cast<const float4*>(
            &W[(size_t)(k0 + wRow) * H_ + colBase + wCol]);
        *reinterpret_cast<float4*>(&Ws[wRow][wCol]) = wv;
        __syncthreads();
#pragma unroll
        for (int kk = 0; kk < BK; ++kk) {
            float a[TM], w[TN];
#pragma unroll
            for (int i = 0; i < TM; ++i) a[i] = As[kk][threadIdx.y * TM + i];
#pragma unroll
            for (int j = 0; j < TN; ++j) w[j] = Ws[kk][threadIdx.x * TN + j];
#pragma unroll
            for (int i = 0; i < TM; ++i)
#pragma unroll
                for (int j = 0; j < TN; ++j)
                    acc[i][j] = fmaf(a[i], w[j], acc[i][j]);
        }
        __syncthreads();
    }
#pragma unroll
    for (int i = 0; i < TM; ++i) {
        const int gr = rowTile + threadIdx.y * TM + i;
        if (gr >= cnt) continue;
#pragma unroll
        for (int j = 0; j < TN; ++j) {
            const int col = colBase + threadIdx.x * TN + j;
            float v = acc[i][j] + bias[col];
            v = (v - mean[col]) * rsqrtf(var[col] + EPS_BN) * g[col] + bt[col];
            outp[(size_t)gr * H_ + col] = fmaxf(v, 0.f);
        }
    }
}

__global__ __launch_bounds__(256)
void refine_gemm2(const float* __restrict__ A, const float* __restrict__ W,
                  const float* __restrict__ bias, const int* __restrict__ counts,
                  float* __restrict__ Cout)
{
    constexpr int BM = 64, BN = 64, BK = 16, TM = 4, TN = 4;
    const int cnt_raw = counts[5];
    const int cnt = cnt_raw > RMAX ? RMAX : cnt_raw;
    const int rowTile = blockIdx.y * BM;
    if (rowTile >= cnt) return;
    __shared__ float As[BK][BM + 4];
    __shared__ float Ws[BK][BN + 4];
    const int tid = threadIdx.y * 16 + threadIdx.x;
    const int colBase = blockIdx.x * BN;
    const int aRow = tid >> 2, aCol = (tid & 3) * 4;
    const int wRow = tid >> 4, wCol = (tid & 15) * 4;
    float acc[TM][TN] = {};

    for (int k0 = 0; k0 < H_; k0 += BK) {
        const float4 av = *reinterpret_cast<const float4*>(
            &A[(size_t)(rowTile + aRow) * H_ + k0 + aCol]);
        As[aCol + 0][aRow] = av.x; As[aCol + 1][aRow] = av.y;
        As[aCol + 2][aRow] = av.z; As[aCol + 3][aRow] = av.w;
        const float4 wv = *reinterpret_cast<const float4*>(
            &W[(size_t)(k0 + wRow) * Z_ + colBase + wCol]);
        *reinterpret_cast<float4*>(&Ws[wRow][wCol]) = wv;
        __syncthreads();
#pragma unroll
        for (int kk = 0; kk < BK; ++kk) {
            float a[TM], w[TN];
#pragma unroll
            for (int i = 0; i < TM; ++i) a[i] = As[kk][threadIdx.y * TM + i];
#pragma unroll
            for (int j = 0; j < TN; ++j) w[j] = Ws[kk][threadIdx.x * TN + j];
#pragma unroll
            for (int i = 0; i < TM; ++i)
#pragma unroll
                for (int j = 0; j < TN; ++j)
                    acc[i][j] = fmaf(a[i], w[j], acc[i][j]);
        }
        __syncthreads();
    }
#pragma unroll
    for (int i = 0; i < TM; ++i) {
        const int row = rowTile + threadIdx.y * TM + i;
#pragma unroll
        for (int j = 0; j < TN; ++j) {
            const int col = colBase + threadIdx.x * TN + j;
            Cout[(size_t)row * Z_ + col] = acc[i][j] + bias[col];
        }
    }
}

// ---------------------------------------------------------------------------
// Fused: L2-norm zp rows (wave per row, 4 rows/block), write out_zp fp32 +
// zpb bf16, pattern logits vs 5 protos, flag near-tied rows.
__global__ __launch_bounds__(256)
void norm_logits(const float* __restrict__ zp, const float* __restrict__ pProto,
                 float* __restrict__ out_zp, unsigned short* __restrict__ zpb,
                 float* __restrict__ out_lp, int* __restrict__ counts,
                 int* __restrict__ rlist)
{
    const int wave = threadIdx.x >> 6, lane = threadIdx.x & 63;
    const int b = blockIdx.x * 4 + wave;
    const float4 v = *(const float4*)&zp[(size_t)b * Z_ + lane * 4];
    float s = v.x * v.x + v.y * v.y + v.z * v.z + v.w * v.w;
    for (int off = 32; off; off >>= 1) s += __shfl_down(s, off);
    s = __shfl(s, 0);
    const float scale = 1.f / fmaxf(sqrtf(s), EPS_NORM);
    float4 z = make_float4(v.x * scale, v.y * scale, v.z * scale, v.w * scale);
    *(float4*)&out_zp[(size_t)b * Z_ + lane * 4] = z;
    ush4 o = { f2bf(z.x), f2bf(z.y), f2bf(z.z), f2bf(z.w) };
    *(ush4*)&zpb[(size_t)b * Z_ + lane * 4] = o;
    float p[E_];
#pragma unroll
    for (int e = 0; e < E_; ++e) {
        const float4 pr = *(const float4*)&pProto[(size_t)e * Z_ + lane * 4];
        float d = z.x * pr.x + z.y * pr.y + z.z * pr.z + z.w * pr.w;
        for (int off = 32; off; off >>= 1) d += __shfl_down(d, off);
        p[e] = d;
    }
    if (lane == 0) {
        float b1 = -1e30f, b2 = -1e30f;
#pragma unroll
        for (int e = 0; e < E_; ++e) {
            out_lp[(size_t)b * E_ + e] = p[e];
            if (p[e] > b1) { b2 = b1; b1 = p[e]; }
            else if (p[e] > b2) b2 = p[e];
        }
        if (b1 - b2 < GAP_TAU) {
            const int i = atomicAdd(&counts[5], 1);
            if (i < RMAX) rlist[i] = b;
        }
    }
}

// Refine finalize: normalize refined row, recompute 5 logits, overwrite out_lp.
__global__ __launch_bounds__(256)
void refine_finalize(const float* __restrict__ tR, const float* __restrict__ pProto,
                     const int* __restrict__ rlist, const int* __restrict__ counts,
                     float* __restrict__ out_lp)
{
    const int cnt_raw = counts[5];
    const int cnt = cnt_raw > RMAX ? RMAX : cnt_raw;
    const int i = blockIdx.x;
    if (i >= cnt) return;
    const int b = rlist[i];
    const int t = threadIdx.x;
    const float v = tR[(size_t)i * Z_ + t];
    __shared__ float wsum[4];
    float s = v * v;
    for (int off = 32; off; off >>= 1) s += __shfl_down(s, off);
    if ((t & 63) == 0) wsum[t >> 6] = s;
    __syncthreads();
    const float scale = 1.f / fmaxf(sqrtf(wsum[0] + wsum[1] + wsum[2] + wsum[3]), EPS_NORM);
    const float z = v * scale;
    for (int e = 0; e < E_; ++e) {
        float d = z * pProto[(size_t)e * Z_ + t];
        for (int off = 32; off; off >>= 1) d += __shfl_down(d, off);
        __syncthreads();
        if ((t & 63) == 0) wsum[t >> 6] = d;
        __syncthreads();
        if (t == 0) out_lp[(size_t)b * E_ + e] = wsum[0] + wsum[1] + wsum[2] + wsum[3];
    }
}

// Final routing from (possibly refined) logits.
__global__ __launch_bounds__(256)
void route_kernel(const float* __restrict__ lp, int* __restrict__ counts,
                  int* __restrict__ lists)
{
    const int b = blockIdx.x * 256 + threadIdx.x;
    const float* p = lp + (size_t)b * E_;
    int best = 0; float bv = p[0];
#pragma unroll
    for (int e = 1; e < E_; ++e) { const float x = p[e]; if (x > bv) { bv = x; best = e; } }
    const int pos = atomicAdd(&counts[best], 1);
    lists[best * B_ + pos] = b;
}

__global__ void calc_offsets(const int* __restrict__ counts, int* __restrict__ offsets) {
    if (threadIdx.x == 0) {
        int acc = 0;
        for (int e = 0; e < E_; ++e) { offsets[e] = acc; acc += counts[e]; }
        offsets[E_] = acc;
    }
}

// ---------------------------------------------------------------------------
// Normalize z2 rows (wave per row, 4 rows/block): scatter out_pf fp32,
// write z2nb bf16 compacted (for class_gemm).
__global__ __launch_bounds__(256)
void finalize_norm(const float* __restrict__ z2c, const int* __restrict__ lists,
                   const int* __restrict__ offsets, float* __restrict__ out_pf,
                   unsigned short* __restrict__ z2nb)
{
    const int wave = threadIdx.x >> 6, lane = threadIdx.x & 63;
    const int c = blockIdx.x * 4 + wave;
    int e = 0;
#pragma unroll
    for (int k = 1; k < E_; ++k) if (c >= offsets[k]) e = k;
    const int b = lists[e * B_ + (c - offsets[e])];
    const float4 v = *(const float4*)&z2c[(size_t)c * Z_ + lane * 4];
    float s = v.x * v.x + v.y * v.y + v.z * v.z + v.w * v.w;
    for (int off = 32; off; off >>= 1) s += __shfl_down(s, off);
    s = __shfl(s, 0);
    const float scale = 1.f / fmaxf(sqrtf(s), EPS_NORM);
    float4 z = make_float4(v.x * scale, v.y * scale, v.z * scale, v.w * scale);
    *(float4*)&out_pf[(size_t)b * Z_ + lane * 4] = z;
    ush4 o = { f2bf(z.x), f2bf(z.y), f2bf(z.z), f2bf(z.w) };
    *(ush4*)&z2nb[(size_t)c * Z_ + lane * 4] = o;
}

// ---------------------------------------------------------------------------
extern "C" void kernel_launch(void* const* d_in, const int* in_sizes, int n_in,
                              void* d_out, int out_size, void* d_ws, size_t ws_size,
                              hipStream_t stream)
{
    const float* feats  = (const float*)d_in[0];
    const float* pW1    = (const float*)d_in[1];
    const float* pb1    = (const float*)d_in[2];
    const float* pg     = (const float*)d_in[3];
    const float* pbt    = (const float*)d_in[4];
    const float* pm     = (const float*)d_in[5];
    const float* pv     = (const float*)d_in[6];
    const float* pW2    = (const float*)d_in[7];
    const float* pb2    = (const float*)d_in[8];
    const float* pProto = (const float*)d_in[9];
    const float* cW1    = (const float*)d_in[10];
    const float* cb1    = (const float*)d_in[11];
    const float* cg     = (const float*)d_in[12];
    const float* cbt    = (const float*)d_in[13];
    const float* cm     = (const float*)d_in[14];
    const float* cv     = (const float*)d_in[15];
    const float* cW2    = (const float*)d_in[16];
    const float* cb2    = (const float*)d_in[17];
    const float* cProto = (const float*)d_in[18];

    // workspace layout (ushort units unless noted)
    unsigned short* fAp  = (unsigned short*)d_ws;                 // B*D*2 ush
    unsigned short* hpk  = fAp  + (size_t)B_ * D_ * 2;            // B*H*2 ush
    unsigned short* W1Tp = hpk  + (size_t)B_ * H_ * 2;            // H*D*2 ush
    unsigned short* W2Tp = W1Tp + (size_t)H_ * D_ * 2;            // Z*H*2 ush
    unsigned short* cW1T = W2Tp + (size_t)Z_ * H_ * 2;            // E*H*Z ush
    unsigned short* cW2T = cW1T + (size_t)E_ * H_ * Z_;           // E*Z*H ush
    unsigned short* cPb  = cW2T + (size_t)E_ * Z_ * H_;           // E*128*Z ush
    unsigned short* zpb  = cPb  + (size_t)E_ * 128 * Z_;          // B*Z ush
    float* zp  = (float*)(zpb + (size_t)B_ * Z_);                 // B*Z f32
    float* z2c = zp + (size_t)B_ * Z_;                            // B*Z f32
    int* counts  = (int*)(z2c + (size_t)B_ * Z_);
    int* offsets = counts + 8;
    int* rlist   = offsets + 8;
    int* lists   = rlist + RMAX;
    // reused regions:
    unsigned short* h2c  = fAp;               // after GEMM1 consumed: B*H bf16
    unsigned short* z2nb = zpb;               // after gemmA consumed: B*Z bf16
    float* hR = (float*)hpk;                  // after GEMM2 consumed: RMAX*H f32
    float* tR = hR + (size_t)RMAX * H_;       // RMAX*Z f32

    float* out_lp = (float*)d_out;
    float* out_zp = out_lp + (size_t)B_ * E_;
    float* out_lc = out_zp + (size_t)B_ * Z_;
    float* out_pf = out_lc + (size_t)B_ * C_;

    // convert / pack (pack_rows also zeroes counters)
    pack_rows<<<(int)(((size_t)B_ * D_) / 2048), 256, 0, stream>>>(feats, fAp, D_, counts);
    tconv_kernel<true ><<<dim3(D_ / 32, H_ / 32, 1), 256, 0, stream>>>(pW1, W1Tp, D_, H_);
    tconv_kernel<true ><<<dim3(H_ / 32, Z_ / 32, 1), 256, 0, stream>>>(pW2, W2Tp, H_, Z_);
    tconv_kernel<false><<<dim3(Z_ / 32, H_ / 32, E_), 256, 0, stream>>>(cW1, cW1T, Z_, H_);
    tconv_kernel<false><<<dim3(H_ / 32, Z_ / 32, E_), 256, 0, stream>>>(cW2, cW2T, H_, Z_);
    conv_cproto<<<E_ * 128, 64, 0, stream>>>(cProto, cPb);

    // pattern head (3-term split bf16 MFMA)
    gemm_split3<128, 128, 0><<<dim3(H_ / 128, B_ / 128), 256, 0, stream>>>(
        fAp, W1Tp, pb1, pg, pbt, pm, pv, hpk, D_, H_);
    gemm_split3<128, 64, 1><<<dim3(Z_ / 64, B_ / 128), 256, 0, stream>>>(
        hpk, W2Tp, pb2, nullptr, nullptr, nullptr, nullptr, zp, H_, Z_);

    // fused normalize + logits + flag
    norm_logits<<<B_ / 4, 256, 0, stream>>>(zp, pProto, out_zp, zpb, out_lp, counts, rlist);

    // exact fp32 recompute for near-tied rows (gated by counts[5])
    refine_gemm1<<<dim3(H_ / 64, RMAX / 64), dim3(16, 16), 0, stream>>>(
        feats, pW1, pb1, pg, pbt, pm, pv, rlist, counts, hR);
    refine_gemm2<<<dim3(Z_ / 64, RMAX / 64), dim3(16, 16), 0, stream>>>(
        hR, pW2, pb2, counts, tR);
    refine_finalize<<<RMAX, 256, 0, stream>>>(tR, pProto, rlist, counts, out_lp);

    // routing + compaction
    route_kernel<<<B_ / 256, 256, 0, stream>>>(out_lp, counts, lists);
    calc_offsets<<<1, 64, 0, stream>>>(counts, offsets);

    // experts (1-term bf16 MFMA; A gathered from zpb via lists)
    gemm_plain1<128, 128, 2, true ><<<dim3(H_ / 128, B_ / 128, E_), 256, 0, stream>>>(
        zpb, cW1T, cb1, cg, cbt, cm, cv, h2c, counts, offsets, lists, Z_, H_);
    gemm_plain1<128, 128, 3, false><<<dim3(Z_ / 128, B_ / 128, E_), 256, 0, stream>>>(
        h2c, cW2T, cb2, nullptr, nullptr, nullptr, nullptr, z2c, counts, offsets, nullptr, H_, Z_);

    // normalize z2 (scatter out_pf, bf16 compacted) + class logits GEMM
    finalize_norm<<<B_ / 4, 256, 0, stream>>>(z2c, lists, offsets, out_pf, z2nb);
    class_gemm<<<dim3(1, B_ / 128, E_), 256, 0, stream>>>(
        z2nb, cPb, counts, offsets, lists, out_lc);
}